// Round 5
// baseline (254.517 us; speedup 1.0000x reference)
//
#include <hip/hip_runtime.h>

#define N_NODES 100000
#define DIM 256
#define KC 16
#define NE 3200000
#define CHUNK 64
#define NCHUNKS ((N_NODES + CHUNK - 1) / CHUNK)   // 1563 (last chunk = 32 nodes)

// LDS layout strides (u16 units)
#define D0STR 1168   // per 16-dim block: 8 groups * 144 + 16 pad  (2336 B)
#define GSTR  144    // per 8-node group: 8*16 + 16 pad            (288 B)
#define PSTR  72     // P' row stride (64 nodes + 8 pad)           (144 B)

using bf16x8 = __attribute__((ext_vector_type(8))) short;
using f32x4  = __attribute__((ext_vector_type(4))) float;

__device__ __forceinline__ unsigned short f2bf(float f) {  // RNE
    unsigned u = __float_as_uint(f);
    return (unsigned short)((u + 0x7fffu + ((u >> 16) & 1u)) >> 16);
}
__device__ __forceinline__ unsigned packbf(float a, float b) {
    return (unsigned)f2bf(a) | ((unsigned)f2bf(b) << 16);
}

// ---------------------------------------------------------------------------
// Fused assignment + S^T X, both phases MFMA. One chunk per block (grid 1563).
//  stage:   reg-staged (2 batches of 8 outstanding dwordx4 loads).
//  phase A: logits^T = W·X^T, mfma(wfrag, xfrag).
//  phase B: st += P'·X (bf16 P', 8 MFMAs).
//  epilogue:
//   WRITE_PART=1: per-block partials -> Pb[b][d][k], plain coalesced float4
//                 stores (NO atomics; round-4 counters showed each stx
//                 atomicAdd = a 4B HBM RMW: WRITE_SIZE delta == atomic count).
//   WRITE_PART=0: legacy atomicAdd path (small-workspace fallback).
// ---------------------------------------------------------------------------
template <bool WRITE_PACK, bool WRITE_PART>
__global__ __launch_bounds__(256, 4) void k_assign_stx(const float4* __restrict__ X4,
                                                       const float4* __restrict__ W4,
                                                       const float* __restrict__ bias,
                                                       float* __restrict__ S,
                                                       unsigned* __restrict__ Sb,
                                                       float* __restrict__ cs_g,
                                                       float* __restrict__ stx,
                                                       float* __restrict__ Pb) {
    __shared__ __align__(16) unsigned short Xs[16 * D0STR];   // 37376 B
    __shared__ __align__(16) unsigned short psb[16 * PSTR];   // 2304 B
    __shared__ float csred[4][KC];                            // 256 B -> 39936 B total

    const int lane = threadIdx.x & 63;
    const int wv   = threadIdx.x >> 6;
    const int c    = lane & 15;
    const int quad = lane >> 4;

    const int base = blockIdx.x * CHUNK;

    // ---- staging geometry
    const int c4  = threadIdx.x & 63;
    const int r0  = threadIdx.x >> 6;
    const int d0s = c4 >> 2;
    const int wo  = (c4 & 3) * 4;

    // ---- batch 1: stage loads (8 outstanding), W loads interleaved
    float4 xr[8];
    #pragma unroll
    for (int s = 0; s < 8; s++) {
        int rg = base + r0 + 4 * s;
        if (rg >= N_NODES) rg = N_NODES - 1;
        xr[s] = X4[(size_t)rg * 64 + c4];
    }
    bf16x8 wfrag[8];
    #pragma unroll
    for (int s = 0; s < 4; s++) {
        float4 wa = W4[c * 64 + s * 8 + quad * 2];
        float4 wb = W4[c * 64 + s * 8 + quad * 2 + 1];
        union { bf16x8 v; unsigned u[4]; } wf;
        wf.u[0] = packbf(wa.x, wa.y);
        wf.u[1] = packbf(wa.z, wa.w);
        wf.u[2] = packbf(wb.x, wb.y);
        wf.u[3] = packbf(wb.z, wb.w);
        wfrag[s] = wf.v;
    }
    #pragma unroll
    for (int s = 0; s < 8; s++) {
        int r = r0 + 4 * s;
        *(uint2*)&Xs[d0s * D0STR + (r >> 3) * GSTR + (r & 7) * 16 + wo] =
            make_uint2(packbf(xr[s].x, xr[s].y), packbf(xr[s].z, xr[s].w));
    }
    // ---- batch 2
    #pragma unroll
    for (int s = 0; s < 8; s++) {
        int rg = base + r0 + 4 * (s + 8);
        if (rg >= N_NODES) rg = N_NODES - 1;
        xr[s] = X4[(size_t)rg * 64 + c4];
    }
    #pragma unroll
    for (int s = 4; s < 8; s++) {
        float4 wa = W4[c * 64 + s * 8 + quad * 2];
        float4 wb = W4[c * 64 + s * 8 + quad * 2 + 1];
        union { bf16x8 v; unsigned u[4]; } wf;
        wf.u[0] = packbf(wa.x, wa.y);
        wf.u[1] = packbf(wa.z, wa.w);
        wf.u[2] = packbf(wb.x, wb.y);
        wf.u[3] = packbf(wb.z, wb.w);
        wfrag[s] = wf.v;
    }
    #pragma unroll
    for (int s = 0; s < 8; s++) {
        int r = r0 + 4 * (s + 8);
        *(uint2*)&Xs[d0s * D0STR + (r >> 3) * GSTR + (r & 7) * 16 + wo] =
            make_uint2(packbf(xr[s].x, xr[s].y), packbf(xr[s].z, xr[s].w));
    }
    const float4 b4 = ((const float4*)bias)[quad];
    __syncthreads();

    // ---- phase A: logits^T (D[m=cluster][n=node]); B-frag = node's dims
    f32x4 la = {0.f, 0.f, 0.f, 0.f};
    {
        const int node = wv * 16 + c;
        const int gA = node >> 3, n8 = node & 7;
        #pragma unroll
        for (int s = 0; s < 8; s++) {
            const int d0 = 2 * s + (quad >> 1);
            bf16x8 xf = *(const bf16x8*)&Xs[d0 * D0STR + gA * GSTR + n8 * 16 + (quad & 1) * 8];
            la = __builtin_amdgcn_mfma_f32_16x16x32_bf16(wfrag[s], xf, la, 0, 0, 0);
        }
    }
    // softmax over clusters (4 regs x 4 quads)
    float lg0 = la[0] + b4.x, lg1 = la[1] + b4.y;
    float lg2 = la[2] + b4.z, lg3 = la[3] + b4.w;
    float mx = fmaxf(fmaxf(lg0, lg1), fmaxf(lg2, lg3));
    mx = fmaxf(mx, __shfl_xor(mx, 16));
    mx = fmaxf(mx, __shfl_xor(mx, 32));
    float e0 = __expf(lg0 - mx), e1 = __expf(lg1 - mx);
    float e2 = __expf(lg2 - mx), e3 = __expf(lg3 - mx);
    float ssum = e0 + e1 + e2 + e3;
    ssum += __shfl_xor(ssum, 16);
    ssum += __shfl_xor(ssum, 32);
    float inv = 1.f / ssum;
    float pvv[4] = {e0 * inv, e1 * inv, e2 * inv, e3 * inv};

    const int nn = wv * 16 + c;
    const int nd = base + nn;
    if (nd >= N_NODES) {
        pvv[0] = pvv[1] = pvv[2] = pvv[3] = 0.f;
    } else {
        *(float4*)&S[(size_t)nd * KC + quad * 4] =
            make_float4(pvv[0], pvv[1], pvv[2], pvv[3]);
        if (WRITE_PACK) {
            unsigned q0 = __float2uint_rn(pvv[0] * 255.f);
            unsigned q1 = __float2uint_rn(pvv[1] * 255.f);
            unsigned q2 = __float2uint_rn(pvv[2] * 255.f);
            unsigned q3 = __float2uint_rn(pvv[3] * 255.f);
            Sb[(size_t)nd * 4 + quad] = q0 | (q1 << 8) | (q2 << 16) | (q3 << 24);
        }
    }
    float csr[4];
    #pragma unroll
    for (int r = 0; r < 4; r++) {
        psb[(quad * 4 + r) * PSTR + nn] = f2bf(pvv[r]);
        csr[r] = pvv[r];
    }
    __syncthreads();   // psb + Xs ready for phase B

    // ---- phase B: acc += P' · X  (M=cluster, N=dim-tile, K=64 nodes)
    f32x4 acc[4];
    #pragma unroll
    for (int t = 0; t < 4; t++) acc[t] = (f32x4){0.f, 0.f, 0.f, 0.f};
    bf16x8 afH[2];
    afH[0] = *(const bf16x8*)&psb[c * PSTR + 0 * 32 + quad * 8];
    afH[1] = *(const bf16x8*)&psb[c * PSTR + 1 * 32 + quad * 8];
    #pragma unroll
    for (int t = 0; t < 4; t++) {
        const int d0  = wv * 4 + t;
        const int dlo = c;                       // dim = d0*16 + c
        union { bf16x8 v; unsigned short h[8]; } bf0, bf1;
        #pragma unroll
        for (int j = 0; j < 8; j++) {
            const int n0 = quad * 8 + j;         // ks=0: nodes 0..31
            bf0.h[j] = Xs[d0 * D0STR + (n0 >> 3) * GSTR + (n0 & 7) * 16 + dlo];
            const int n1 = 32 + n0;              // ks=1: nodes 32..63
            bf1.h[j] = Xs[d0 * D0STR + (n1 >> 3) * GSTR + (n1 & 7) * 16 + dlo];
        }
        acc[t] = __builtin_amdgcn_mfma_f32_16x16x32_bf16(afH[0], bf0.v, acc[t], 0, 0, 0);
        acc[t] = __builtin_amdgcn_mfma_f32_16x16x32_bf16(afH[1], bf1.v, acc[t], 0, 0, 0);
    }

    // ---- epilogue
    if (WRITE_PART) {
        // Pb[b][d][k]: coalesced float4 stores (wave covers 4KB contiguous)
        #pragma unroll
        for (int t = 0; t < 4; t++) {
            *(float4*)&Pb[((size_t)blockIdx.x * 256 + (wv * 4 + t) * 16 + c) * 16 + quad * 4] =
                make_float4(acc[t][0], acc[t][1], acc[t][2], acc[t][3]);
        }
    } else {
        #pragma unroll
        for (int t = 0; t < 4; t++) {
            #pragma unroll
            for (int r = 0; r < 4; r++)
                atomicAdd(&stx[(quad * 4 + r) * DIM + (wv * 4 + t) * 16 + c], acc[t][r]);
        }
    }

    float csr2[4];
    #pragma unroll
    for (int r = 0; r < 4; r++) {
        float v = csr[r];
        v += __shfl_xor(v, 1); v += __shfl_xor(v, 2);
        v += __shfl_xor(v, 4); v += __shfl_xor(v, 8);
        csr2[r] = v;
    }
    if (c == 0) {
        #pragma unroll
        for (int r = 0; r < 4; r++) csred[wv][quad * 4 + r] = csr2[r];
    }
    __syncthreads();
    if (threadIdx.x < KC) {
        int t = threadIdx.x;
        atomicAdd(&cs_g[t], csred[0][t] + csred[1][t] + csred[2][t] + csred[3][t]);
    }
}

// ---------------------------------------------------------------------------
// Reduce partials: stx[k][d] = sum_b Pb[b][d][k]; then selu(stx/cs) -> out.
// Grid 256 (one d per block). Coalesced: 16 lanes read 64B contiguous per b.
// ---------------------------------------------------------------------------
__global__ __launch_bounds__(256) void k_reduce(const float* __restrict__ Pb,
                                                const float* __restrict__ cs,
                                                float* __restrict__ out) {
    const int d  = blockIdx.x;
    const int k  = threadIdx.x & 15;
    const int bg = threadIdx.x >> 4;   // 16 b-groups
    float s = 0.f;
    for (int b = bg; b < NCHUNKS; b += 16)
        s += Pb[((size_t)b * 256 + d) * 16 + k];
    __shared__ float red[16][17];
    red[bg][k] = s;
    __syncthreads();
    if (threadIdx.x < 16) {
        float v = 0.f;
        #pragma unroll
        for (int g = 0; g < 16; g++) v += red[g][threadIdx.x];
        float q = v / cs[threadIdx.x];
        float r = (q > 0.f) ? 1.0507009873554805f * q
                            : 1.7580993408473766f * (__expf(q) - 1.f);
        out[threadIdx.x * DIM + d] = r;
    }
}

// ---------------------------------------------------------------------------
// Losses only (partial path; selu done in k_reduce)
// ---------------------------------------------------------------------------
__global__ void k_losses(const float* __restrict__ cs,
                         const float* __restrict__ left,
                         const float* __restrict__ m2p,
                         const float* __restrict__ trp,
                         float* __restrict__ out) {
    if (threadIdx.x == 0) {
        float m2 = *m2p;
        float tn = 0.f;
        #pragma unroll
        for (int k = 0; k < KC; k++) tn += left[k] * left[k];
        tn /= m2;
        float spectral = -((*trp) - tn) / m2;
        float ss = 0.f;
        #pragma unroll
        for (int k = 0; k < KC; k++) ss += cs[k] * cs[k];
        float collapse = 0.1f * (sqrtf(ss) / (float)N_NODES * 4.0f - 1.0f);
        out[KC * DIM + (size_t)N_NODES * KC]     = spectral;
        out[KC * DIM + (size_t)N_NODES * KC + 1] = collapse;
    }
}

// ---------------------------------------------------------------------------
// Per-edge fused (u8-packed S): one uint4 gather per node, 2 edges/iter
// (validated round 1/3 form; round-4 4-edge showed no wall gain).
// ---------------------------------------------------------------------------
__device__ __forceinline__ void edge_acc_u8(uint4 qr, uint4 qc, float a,
                                            float (&lf)[KC], float& m2l, float& trl) {
    union { uint4 v; unsigned w[4]; } R, C;
    R.v = qr; C.v = qc;
    float dd = 0.f;
    #pragma unroll
    for (int q = 0; q < 4; q++) {
        unsigned x = R.w[q], y = C.w[q];
        float s0 = (float)(x & 0xffu);
        float s1 = (float)((x >> 8) & 0xffu);
        float s2 = (float)((x >> 16) & 0xffu);
        float s3 = (float)(x >> 24);
        float c0 = (float)(y & 0xffu);
        float c1 = (float)((y >> 8) & 0xffu);
        float c2 = (float)((y >> 16) & 0xffu);
        float c3 = (float)(y >> 24);
        dd = fmaf(s0, c0, dd); dd = fmaf(s1, c1, dd);
        dd = fmaf(s2, c2, dd); dd = fmaf(s3, c3, dd);
        lf[4 * q + 0] = fmaf(a, s0, lf[4 * q + 0]);
        lf[4 * q + 1] = fmaf(a, s1, lf[4 * q + 1]);
        lf[4 * q + 2] = fmaf(a, s2, lf[4 * q + 2]);
        lf[4 * q + 3] = fmaf(a, s3, lf[4 * q + 3]);
    }
    m2l += a;
    trl = fmaf(a, dd, trl);
}

__global__ __launch_bounds__(256) void k_edges_u8(const int* __restrict__ rows,
                                                  const int* __restrict__ cols,
                                                  const float* __restrict__ adj,
                                                  const uint4* __restrict__ Sb4,
                                                  float* __restrict__ m2_g,
                                                  float* __restrict__ tr_g,
                                                  float* __restrict__ left_g) {
    float m2l = 0.f, trl = 0.f;
    float lf[KC];
    #pragma unroll
    for (int k = 0; k < KC; k++) lf[k] = 0.f;

    const int NU = NE / 2;
    const int stride = gridDim.x * blockDim.x;
    for (int u = blockIdx.x * blockDim.x + threadIdx.x; u < NU; u += stride) {
        int2   r2 = *(const int2*)(rows + 2 * (size_t)u);
        int2   c2 = *(const int2*)(cols + 2 * (size_t)u);
        float2 a2 = *(const float2*)(adj + 2 * (size_t)u);
        uint4 qr0 = Sb4[r2.x];
        uint4 qc0 = Sb4[c2.x];
        uint4 qr1 = Sb4[r2.y];
        uint4 qc1 = Sb4[c2.y];
        edge_acc_u8(qr0, qc0, a2.x, lf, m2l, trl);
        edge_acc_u8(qr1, qc1, a2.y, lf, m2l, trl);
    }

    trl *= (1.f / 65025.f);
    #pragma unroll
    for (int k = 0; k < KC; k++) lf[k] *= (1.f / 255.f);

    #pragma unroll
    for (int off = 32; off >= 1; off >>= 1) {
        m2l += __shfl_xor(m2l, off);
        trl += __shfl_xor(trl, off);
    }
    #pragma unroll
    for (int k = 0; k < KC; k++) {
        float v = lf[k];
        #pragma unroll
        for (int off = 32; off >= 1; off >>= 1) v += __shfl_xor(v, off);
        lf[k] = v;
    }
    __shared__ float red[4][18];
    int w = threadIdx.x >> 6;
    if ((threadIdx.x & 63) == 0) {
        red[w][0] = m2l; red[w][1] = trl;
        #pragma unroll
        for (int k = 0; k < KC; k++) red[w][2 + k] = lf[k];
    }
    __syncthreads();
    int t = threadIdx.x;
    if (t < 18) {
        float v = red[0][t] + red[1][t] + red[2][t] + red[3][t];
        float* dst = (t == 0) ? m2_g : (t == 1) ? tr_g : &left_g[t - 2];
        atomicAdd(dst, v);
    }
}

// ---------------------------------------------------------------------------
// f32 fallback edge kernel (workspace too small for Sb)
// ---------------------------------------------------------------------------
__global__ __launch_bounds__(256) void k_edges_f32(const int* __restrict__ rows,
                                                   const int* __restrict__ cols,
                                                   const float* __restrict__ adj,
                                                   const float* __restrict__ S,
                                                   float* __restrict__ m2_g,
                                                   float* __restrict__ tr_g,
                                                   float* __restrict__ left_g) {
    float m2l = 0.f, trl = 0.f;
    float lf[KC];
    #pragma unroll
    for (int k = 0; k < KC; k++) lf[k] = 0.f;

    int stride = gridDim.x * blockDim.x;
    for (int e = blockIdx.x * blockDim.x + threadIdx.x; e < NE; e += stride) {
        int r = rows[e], c = cols[e];
        float a = adj[e];
        float sv[KC], cv[KC];
        const float4* sr = (const float4*)(S + (size_t)r * KC);
        const float4* sc = (const float4*)(S + (size_t)c * KC);
        #pragma unroll
        for (int qq = 0; qq < 4; qq++) {
            float4 s4 = sr[qq], c4 = sc[qq];
            sv[4*qq]=s4.x; sv[4*qq+1]=s4.y; sv[4*qq+2]=s4.z; sv[4*qq+3]=s4.w;
            cv[4*qq]=c4.x; cv[4*qq+1]=c4.y; cv[4*qq+2]=c4.z; cv[4*qq+3]=c4.w;
        }
        float dd = 0.f;
        #pragma unroll
        for (int k = 0; k < KC; k++) {
            dd += sv[k] * cv[k];
            lf[k] += a * sv[k];
        }
        m2l += a;
        trl += a * dd;
    }

    #pragma unroll
    for (int off = 32; off >= 1; off >>= 1) {
        m2l += __shfl_xor(m2l, off);
        trl += __shfl_xor(trl, off);
    }
    #pragma unroll
    for (int k = 0; k < KC; k++) {
        float v = lf[k];
        #pragma unroll
        for (int off = 32; off >= 1; off >>= 1) v += __shfl_xor(v, off);
        lf[k] = v;
    }
    __shared__ float red[4][18];
    int w = threadIdx.x >> 6;
    if ((threadIdx.x & 63) == 0) {
        red[w][0] = m2l; red[w][1] = trl;
        #pragma unroll
        for (int k = 0; k < KC; k++) red[w][2 + k] = lf[k];
    }
    __syncthreads();
    int t = threadIdx.x;
    if (t < 18) {
        float v = red[0][t] + red[1][t] + red[2][t] + red[3][t];
        float* dst = (t == 0) ? m2_g : (t == 1) ? tr_g : &left_g[t - 2];
        atomicAdd(dst, v);
    }
}

// ---------------------------------------------------------------------------
// legacy epilogue (atomic-stx fallback): selu + losses
// ---------------------------------------------------------------------------
__global__ __launch_bounds__(256) void k_final(const float* __restrict__ cs,
                                               const float* __restrict__ left,
                                               const float* __restrict__ m2p,
                                               const float* __restrict__ trp,
                                               const float* __restrict__ stx,
                                               float* __restrict__ out) {
    int t = threadIdx.x;
    #pragma unroll
    for (int k = 0; k < KC; k++) {
        float v = stx[k * DIM + t] / cs[k];
        float r = (v > 0.f) ? 1.0507009873554805f * v
                            : 1.7580993408473766f * (__expf(v) - 1.f);
        out[k * DIM + t] = r;
    }
    if (t == 0) {
        float m2 = *m2p;
        float tn = 0.f;
        #pragma unroll
        for (int k = 0; k < KC; k++) tn += left[k] * left[k];
        tn /= m2;
        float spectral = -((*trp) - tn) / m2;
        float ss = 0.f;
        #pragma unroll
        for (int k = 0; k < KC; k++) ss += cs[k] * cs[k];
        float collapse = 0.1f * (sqrtf(ss) / (float)N_NODES * 4.0f - 1.0f);
        out[KC * DIM + (size_t)N_NODES * KC]     = spectral;
        out[KC * DIM + (size_t)N_NODES * KC + 1] = collapse;
    }
}

extern "C" void kernel_launch(void* const* d_in, const int* in_sizes, int n_in,
                              void* d_out, int out_size, void* d_ws, size_t ws_size,
                              hipStream_t stream) {
    (void)out_size;

    const float* X    = nullptr;
    const int*   ei   = nullptr;
    const float* adj  = nullptr;
    const float* W    = nullptr;
    const float* bias = nullptr;
    for (int i = 0; i < n_in; i++) {
        switch (in_sizes[i]) {
            case 25600000: X    = (const float*)d_in[i]; break;
            case  6400000: ei   = (const int*)d_in[i];   break;
            case  3200000: adj  = (const float*)d_in[i]; break;
            case     4096: W    = (const float*)d_in[i]; break;
            case       16: bias = (const float*)d_in[i]; break;
        }
    }

    float* out = (float*)d_out;
    float* S   = out + KC * DIM;    // assignments [100000,16] f32
    const int* rows = ei;
    const int* cols = ei + NE;

    float* ws   = (float*)d_ws;
    float* cs   = ws;
    float* left = ws + 16;
    float* m2   = ws + 32;
    float* tr   = ws + 33;
    float* stx  = ws + 64;
    unsigned* Sb = (unsigned*)(ws + 64 + KC * DIM);       // u8-packed S, 16 B/node
    float* Pb    = (float*)(Sb + (size_t)N_NODES * 4);    // partials [1563][256][16]
    const size_t need_pack = (64 + KC * DIM) * sizeof(float) + (size_t)N_NODES * 16;
    const size_t need_part = need_pack + (size_t)NCHUNKS * 4096 * sizeof(float);
    const bool use_pack = (ws_size >= need_pack);   // fixed per process -> graph-safe
    const bool use_part = (ws_size >= need_part);

    hipMemsetAsync(d_ws, 0, (64 + KC * DIM) * sizeof(float), stream);

    if (use_part) {
        k_assign_stx<true, true><<<NCHUNKS, 256, 0, stream>>>(
            (const float4*)X, (const float4*)W, bias, S, Sb, cs, stx, Pb);
        k_edges_u8<<<2048, 256, 0, stream>>>(rows, cols, adj, (const uint4*)Sb,
                                             m2, tr, left);
        k_reduce<<<DIM, 256, 0, stream>>>(Pb, cs, out);
        k_losses<<<1, 64, 0, stream>>>(cs, left, m2, tr, out);
    } else if (use_pack) {
        k_assign_stx<true, false><<<NCHUNKS, 256, 0, stream>>>(
            (const float4*)X, (const float4*)W, bias, S, Sb, cs, stx, nullptr);
        k_edges_u8<<<2048, 256, 0, stream>>>(rows, cols, adj, (const uint4*)Sb,
                                             m2, tr, left);
        k_final<<<1, 256, 0, stream>>>(cs, left, m2, tr, stx, out);
    } else {
        k_assign_stx<false, false><<<NCHUNKS, 256, 0, stream>>>(
            (const float4*)X, (const float4*)W, bias, S, Sb, cs, stx, nullptr);
        k_edges_f32<<<2048, 256, 0, stream>>>(rows, cols, adj, S, m2, tr, left);
        k_final<<<1, 256, 0, stream>>>(cs, left, m2, tr, stx, out);
    }
}

// Round 6
// 244.410 us; speedup vs baseline: 1.0414x; 1.0414x over previous
//
#include <hip/hip_runtime.h>

#define N_NODES 100000
#define DIM 256
#define KC 16
#define NE 3200000
#define CHUNK 64
#define NCHUNKS ((N_NODES + CHUNK - 1) / CHUNK)   // 1563 (last chunk = 32 nodes)

// LDS layout strides (u16 units)
#define D0STR 1168   // per 16-dim block: 8 groups * 144 + 16 pad  (2336 B)
#define GSTR  144    // per 8-node group: 8*16 + 16 pad            (288 B)
#define PSTR  72     // P' row stride (64 nodes + 8 pad)           (144 B)

using bf16x8 = __attribute__((ext_vector_type(8))) short;
using f32x4  = __attribute__((ext_vector_type(4))) float;

__device__ __forceinline__ unsigned short f2bf(float f) {  // RNE
    unsigned u = __float_as_uint(f);
    return (unsigned short)((u + 0x7fffu + ((u >> 16) & 1u)) >> 16);
}
__device__ __forceinline__ unsigned packbf(float a, float b) {
    return (unsigned)f2bf(a) | ((unsigned)f2bf(b) << 16);
}

// ---------------------------------------------------------------------------
// Fused assignment + S^T X, both phases MFMA. One chunk per block (grid 1563).
//  stage: wave w stages rows w*16..w*16+15 (1KB contiguous per instr); ALL 16
//         loads issued before any LDS write -> ONE latency exposure. W frags
//         loaded/packed first (keeps peak VGPR ~116 < 128).
//         Phase A reads only the wave's own rows -> NO barrier before A.
//  phase A: logits^T = W·X^T, mfma(wfrag, xfrag).
//  phase B: st += P'·X (bf16 P', 8 MFMAs) after the single barrier
//           (psb + cross-wave Xs).
//  epilogue: atomicAdd stx (r5 showed the Pb-partials round-trip costs more
//            than the 6.4M atomic RMWs: wall 254.5 vs 248.0).
// ---------------------------------------------------------------------------
template <bool WRITE_PACK>
__global__ __launch_bounds__(256, 4) void k_assign_stx(const float4* __restrict__ X4,
                                                       const float4* __restrict__ W4,
                                                       const float* __restrict__ bias,
                                                       float* __restrict__ S,
                                                       unsigned* __restrict__ Sb,
                                                       float* __restrict__ cs_g,
                                                       float* __restrict__ stx) {
    __shared__ __align__(16) unsigned short Xs[16 * D0STR];   // 37376 B
    __shared__ __align__(16) unsigned short psb[16 * PSTR];   // 2304 B
    __shared__ float csred[4][KC];                            // 256 B -> 39936 B total

    const int lane = threadIdx.x & 63;
    const int wv   = threadIdx.x >> 6;
    const int c    = lane & 15;
    const int quad = lane >> 4;

    const int base = blockIdx.x * CHUNK;

    // ---- W -> 8 register frags first (4KB, L2-hot after first blocks)
    bf16x8 wfrag[8];
    #pragma unroll
    for (int s = 0; s < 8; s++) {
        float4 wa = W4[c * 64 + s * 8 + quad * 2];
        float4 wb = W4[c * 64 + s * 8 + quad * 2 + 1];
        union { bf16x8 v; unsigned u[4]; } wf;
        wf.u[0] = packbf(wa.x, wa.y);
        wf.u[1] = packbf(wa.z, wa.w);
        wf.u[2] = packbf(wb.x, wb.y);
        wf.u[3] = packbf(wb.z, wb.w);
        wfrag[s] = wf.v;
    }
    const float4 b4 = ((const float4*)bias)[quad];

    // ---- stage: wave wv owns rows wv*16..wv*16+15; 16 loads in flight
    const int c4 = lane;                // 0..63: f4 column within row
    const int d0s = c4 >> 2;
    const int wo  = (c4 & 3) * 4;
    float4 xr[16];
    #pragma unroll
    for (int s = 0; s < 16; s++) {
        int rg = base + wv * 16 + s;
        if (rg >= N_NODES) rg = N_NODES - 1;
        xr[s] = X4[(size_t)rg * 64 + c4];
    }
    #pragma unroll
    for (int s = 0; s < 16; s++) {
        int r = wv * 16 + s;
        *(uint2*)&Xs[d0s * D0STR + (r >> 3) * GSTR + (r & 7) * 16 + wo] =
            make_uint2(packbf(xr[s].x, xr[s].y), packbf(xr[s].z, xr[s].w));
    }
    // NO __syncthreads: phase A consumes only this wave's own rows; the
    // within-wave ds_write -> ds_read ordering is enforced by lgkmcnt waits.

    // ---- phase A: logits^T (D[m=cluster][n=node]); B-frag = node's dims
    f32x4 la = {0.f, 0.f, 0.f, 0.f};
    {
        const int node = wv * 16 + c;
        const int gA = node >> 3, n8 = node & 7;
        #pragma unroll
        for (int s = 0; s < 8; s++) {
            const int d0 = 2 * s + (quad >> 1);
            bf16x8 xf = *(const bf16x8*)&Xs[d0 * D0STR + gA * GSTR + n8 * 16 + (quad & 1) * 8];
            la = __builtin_amdgcn_mfma_f32_16x16x32_bf16(wfrag[s], xf, la, 0, 0, 0);
        }
    }
    // softmax over clusters (4 regs x 4 quads)
    float lg0 = la[0] + b4.x, lg1 = la[1] + b4.y;
    float lg2 = la[2] + b4.z, lg3 = la[3] + b4.w;
    float mx = fmaxf(fmaxf(lg0, lg1), fmaxf(lg2, lg3));
    mx = fmaxf(mx, __shfl_xor(mx, 16));
    mx = fmaxf(mx, __shfl_xor(mx, 32));
    float e0 = __expf(lg0 - mx), e1 = __expf(lg1 - mx);
    float e2 = __expf(lg2 - mx), e3 = __expf(lg3 - mx);
    float ssum = e0 + e1 + e2 + e3;
    ssum += __shfl_xor(ssum, 16);
    ssum += __shfl_xor(ssum, 32);
    float inv = 1.f / ssum;
    float pvv[4] = {e0 * inv, e1 * inv, e2 * inv, e3 * inv};

    const int nn = wv * 16 + c;
    const int nd = base + nn;
    if (nd >= N_NODES) {
        pvv[0] = pvv[1] = pvv[2] = pvv[3] = 0.f;
    } else {
        *(float4*)&S[(size_t)nd * KC + quad * 4] =
            make_float4(pvv[0], pvv[1], pvv[2], pvv[3]);
        if (WRITE_PACK) {
            unsigned q0 = __float2uint_rn(pvv[0] * 255.f);
            unsigned q1 = __float2uint_rn(pvv[1] * 255.f);
            unsigned q2 = __float2uint_rn(pvv[2] * 255.f);
            unsigned q3 = __float2uint_rn(pvv[3] * 255.f);
            Sb[(size_t)nd * 4 + quad] = q0 | (q1 << 8) | (q2 << 16) | (q3 << 24);
        }
    }
    float csr[4];
    #pragma unroll
    for (int r = 0; r < 4; r++) {
        psb[(quad * 4 + r) * PSTR + nn] = f2bf(pvv[r]);
        csr[r] = pvv[r];
    }
    __syncthreads();   // psb ready + Xs visible cross-wave for phase B

    // ---- phase B: acc += P' · X  (M=cluster, N=dim-tile, K=64 nodes)
    f32x4 acc[4];
    #pragma unroll
    for (int t = 0; t < 4; t++) acc[t] = (f32x4){0.f, 0.f, 0.f, 0.f};
    bf16x8 afH[2];
    afH[0] = *(const bf16x8*)&psb[c * PSTR + 0 * 32 + quad * 8];
    afH[1] = *(const bf16x8*)&psb[c * PSTR + 1 * 32 + quad * 8];
    #pragma unroll
    for (int t = 0; t < 4; t++) {
        const int d0  = wv * 4 + t;
        const int dlo = c;                       // dim = d0*16 + c
        union { bf16x8 v; unsigned short h[8]; } bf0, bf1;
        #pragma unroll
        for (int j = 0; j < 8; j++) {
            const int n0 = quad * 8 + j;         // ks=0: nodes 0..31
            bf0.h[j] = Xs[d0 * D0STR + (n0 >> 3) * GSTR + (n0 & 7) * 16 + dlo];
            const int n1 = 32 + n0;              // ks=1: nodes 32..63
            bf1.h[j] = Xs[d0 * D0STR + (n1 >> 3) * GSTR + (n1 & 7) * 16 + dlo];
        }
        acc[t] = __builtin_amdgcn_mfma_f32_16x16x32_bf16(afH[0], bf0.v, acc[t], 0, 0, 0);
        acc[t] = __builtin_amdgcn_mfma_f32_16x16x32_bf16(afH[1], bf1.v, acc[t], 0, 0, 0);
    }

    // ---- epilogue: atomic pass for st; cluster sizes
    #pragma unroll
    for (int t = 0; t < 4; t++) {
        #pragma unroll
        for (int r = 0; r < 4; r++)
            atomicAdd(&stx[(quad * 4 + r) * DIM + (wv * 4 + t) * 16 + c], acc[t][r]);
    }

    float csr2[4];
    #pragma unroll
    for (int r = 0; r < 4; r++) {
        float v = csr[r];
        v += __shfl_xor(v, 1); v += __shfl_xor(v, 2);
        v += __shfl_xor(v, 4); v += __shfl_xor(v, 8);
        csr2[r] = v;
    }
    if (c == 0) {
        #pragma unroll
        for (int r = 0; r < 4; r++) csred[wv][quad * 4 + r] = csr2[r];
    }
    __syncthreads();
    if (threadIdx.x < KC) {
        int t = threadIdx.x;
        atomicAdd(&cs_g[t], csred[0][t] + csred[1][t] + csred[2][t] + csred[3][t]);
    }
}

// ---------------------------------------------------------------------------
// Per-edge fused (u8-packed S): one uint4 gather per node, 2 edges/iter.
// ---------------------------------------------------------------------------
__device__ __forceinline__ void edge_acc_u8(uint4 qr, uint4 qc, float a,
                                            float (&lf)[KC], float& m2l, float& trl) {
    union { uint4 v; unsigned w[4]; } R, C;
    R.v = qr; C.v = qc;
    float dd = 0.f;
    #pragma unroll
    for (int q = 0; q < 4; q++) {
        unsigned x = R.w[q], y = C.w[q];
        float s0 = (float)(x & 0xffu);
        float s1 = (float)((x >> 8) & 0xffu);
        float s2 = (float)((x >> 16) & 0xffu);
        float s3 = (float)(x >> 24);
        float c0 = (float)(y & 0xffu);
        float c1 = (float)((y >> 8) & 0xffu);
        float c2 = (float)((y >> 16) & 0xffu);
        float c3 = (float)(y >> 24);
        dd = fmaf(s0, c0, dd); dd = fmaf(s1, c1, dd);
        dd = fmaf(s2, c2, dd); dd = fmaf(s3, c3, dd);
        lf[4 * q + 0] = fmaf(a, s0, lf[4 * q + 0]);
        lf[4 * q + 1] = fmaf(a, s1, lf[4 * q + 1]);
        lf[4 * q + 2] = fmaf(a, s2, lf[4 * q + 2]);
        lf[4 * q + 3] = fmaf(a, s3, lf[4 * q + 3]);
    }
    m2l += a;
    trl = fmaf(a, dd, trl);
}

__global__ __launch_bounds__(256) void k_edges_u8(const int* __restrict__ rows,
                                                  const int* __restrict__ cols,
                                                  const float* __restrict__ adj,
                                                  const uint4* __restrict__ Sb4,
                                                  float* __restrict__ m2_g,
                                                  float* __restrict__ tr_g,
                                                  float* __restrict__ left_g) {
    float m2l = 0.f, trl = 0.f;
    float lf[KC];
    #pragma unroll
    for (int k = 0; k < KC; k++) lf[k] = 0.f;

    const int NU = NE / 2;
    const int stride = gridDim.x * blockDim.x;
    for (int u = blockIdx.x * blockDim.x + threadIdx.x; u < NU; u += stride) {
        int2   r2 = *(const int2*)(rows + 2 * (size_t)u);
        int2   c2 = *(const int2*)(cols + 2 * (size_t)u);
        float2 a2 = *(const float2*)(adj + 2 * (size_t)u);
        uint4 qr0 = Sb4[r2.x];
        uint4 qc0 = Sb4[c2.x];
        uint4 qr1 = Sb4[r2.y];
        uint4 qc1 = Sb4[c2.y];
        edge_acc_u8(qr0, qc0, a2.x, lf, m2l, trl);
        edge_acc_u8(qr1, qc1, a2.y, lf, m2l, trl);
    }

    trl *= (1.f / 65025.f);
    #pragma unroll
    for (int k = 0; k < KC; k++) lf[k] *= (1.f / 255.f);

    #pragma unroll
    for (int off = 32; off >= 1; off >>= 1) {
        m2l += __shfl_xor(m2l, off);
        trl += __shfl_xor(trl, off);
    }
    #pragma unroll
    for (int k = 0; k < KC; k++) {
        float v = lf[k];
        #pragma unroll
        for (int off = 32; off >= 1; off >>= 1) v += __shfl_xor(v, off);
        lf[k] = v;
    }
    __shared__ float red[4][18];
    int w = threadIdx.x >> 6;
    if ((threadIdx.x & 63) == 0) {
        red[w][0] = m2l; red[w][1] = trl;
        #pragma unroll
        for (int k = 0; k < KC; k++) red[w][2 + k] = lf[k];
    }
    __syncthreads();
    int t = threadIdx.x;
    if (t < 18) {
        float v = red[0][t] + red[1][t] + red[2][t] + red[3][t];
        float* dst = (t == 0) ? m2_g : (t == 1) ? tr_g : &left_g[t - 2];
        atomicAdd(dst, v);
    }
}

// ---------------------------------------------------------------------------
// f32 fallback edge kernel (workspace too small for Sb)
// ---------------------------------------------------------------------------
__global__ __launch_bounds__(256) void k_edges_f32(const int* __restrict__ rows,
                                                   const int* __restrict__ cols,
                                                   const float* __restrict__ adj,
                                                   const float* __restrict__ S,
                                                   float* __restrict__ m2_g,
                                                   float* __restrict__ tr_g,
                                                   float* __restrict__ left_g) {
    float m2l = 0.f, trl = 0.f;
    float lf[KC];
    #pragma unroll
    for (int k = 0; k < KC; k++) lf[k] = 0.f;

    int stride = gridDim.x * blockDim.x;
    for (int e = blockIdx.x * blockDim.x + threadIdx.x; e < NE; e += stride) {
        int r = rows[e], c = cols[e];
        float a = adj[e];
        float sv[KC], cv[KC];
        const float4* sr = (const float4*)(S + (size_t)r * KC);
        const float4* sc = (const float4*)(S + (size_t)c * KC);
        #pragma unroll
        for (int qq = 0; qq < 4; qq++) {
            float4 s4 = sr[qq], c4 = sc[qq];
            sv[4*qq]=s4.x; sv[4*qq+1]=s4.y; sv[4*qq+2]=s4.z; sv[4*qq+3]=s4.w;
            cv[4*qq]=c4.x; cv[4*qq+1]=c4.y; cv[4*qq+2]=c4.z; cv[4*qq+3]=c4.w;
        }
        float dd = 0.f;
        #pragma unroll
        for (int k = 0; k < KC; k++) {
            dd += sv[k] * cv[k];
            lf[k] += a * sv[k];
        }
        m2l += a;
        trl += a * dd;
    }

    #pragma unroll
    for (int off = 32; off >= 1; off >>= 1) {
        m2l += __shfl_xor(m2l, off);
        trl += __shfl_xor(trl, off);
    }
    #pragma unroll
    for (int k = 0; k < KC; k++) {
        float v = lf[k];
        #pragma unroll
        for (int off = 32; off >= 1; off >>= 1) v += __shfl_xor(v, off);
        lf[k] = v;
    }
    __shared__ float red[4][18];
    int w = threadIdx.x >> 6;
    if ((threadIdx.x & 63) == 0) {
        red[w][0] = m2l; red[w][1] = trl;
        #pragma unroll
        for (int k = 0; k < KC; k++) red[w][2 + k] = lf[k];
    }
    __syncthreads();
    int t = threadIdx.x;
    if (t < 18) {
        float v = red[0][t] + red[1][t] + red[2][t] + red[3][t];
        float* dst = (t == 0) ? m2_g : (t == 1) ? tr_g : &left_g[t - 2];
        atomicAdd(dst, v);
    }
}

// ---------------------------------------------------------------------------
// epilogue: features_pooled = selu(stx/cs), spectral & collapse losses (f32)
// ---------------------------------------------------------------------------
__global__ __launch_bounds__(256) void k_final(const float* __restrict__ cs,
                                               const float* __restrict__ left,
                                               const float* __restrict__ m2p,
                                               const float* __restrict__ trp,
                                               const float* __restrict__ stx,
                                               float* __restrict__ out) {
    int t = threadIdx.x;
    #pragma unroll
    for (int k = 0; k < KC; k++) {
        float v = stx[k * DIM + t] / cs[k];
        float r = (v > 0.f) ? 1.0507009873554805f * v
                            : 1.7580993408473766f * (__expf(v) - 1.f);
        out[k * DIM + t] = r;
    }
    if (t == 0) {
        float m2 = *m2p;
        float tn = 0.f;
        #pragma unroll
        for (int k = 0; k < KC; k++) tn += left[k] * left[k];
        tn /= m2;
        float spectral = -((*trp) - tn) / m2;
        float ss = 0.f;
        #pragma unroll
        for (int k = 0; k < KC; k++) ss += cs[k] * cs[k];
        float collapse = 0.1f * (sqrtf(ss) / (float)N_NODES * 4.0f - 1.0f);
        out[KC * DIM + (size_t)N_NODES * KC]     = spectral;
        out[KC * DIM + (size_t)N_NODES * KC + 1] = collapse;
    }
}

extern "C" void kernel_launch(void* const* d_in, const int* in_sizes, int n_in,
                              void* d_out, int out_size, void* d_ws, size_t ws_size,
                              hipStream_t stream) {
    (void)out_size;

    const float* X    = nullptr;
    const int*   ei   = nullptr;
    const float* adj  = nullptr;
    const float* W    = nullptr;
    const float* bias = nullptr;
    for (int i = 0; i < n_in; i++) {
        switch (in_sizes[i]) {
            case 25600000: X    = (const float*)d_in[i]; break;
            case  6400000: ei   = (const int*)d_in[i];   break;
            case  3200000: adj  = (const float*)d_in[i]; break;
            case     4096: W    = (const float*)d_in[i]; break;
            case       16: bias = (const float*)d_in[i]; break;
        }
    }

    float* out = (float*)d_out;
    float* S   = out + KC * DIM;    // assignments [100000,16] f32
    const int* rows = ei;
    const int* cols = ei + NE;

    float* ws   = (float*)d_ws;
    float* cs   = ws;
    float* left = ws + 16;
    float* m2   = ws + 32;
    float* tr   = ws + 33;
    float* stx  = ws + 64;
    unsigned* Sb = (unsigned*)(ws + 64 + KC * DIM);   // u8-packed S, 16 B/node
    const size_t need = (64 + KC * DIM) * sizeof(float) + (size_t)N_NODES * 16;
    const bool use_pack = (ws_size >= need);   // fixed per process -> graph-safe

    hipMemsetAsync(d_ws, 0, (64 + KC * DIM) * sizeof(float), stream);

    if (use_pack) {
        k_assign_stx<true><<<NCHUNKS, 256, 0, stream>>>(
            (const float4*)X, (const float4*)W, bias, S, Sb, cs, stx);
        k_edges_u8<<<2048, 256, 0, stream>>>(rows, cols, adj, (const uint4*)Sb,
                                             m2, tr, left);
    } else {
        k_assign_stx<false><<<NCHUNKS, 256, 0, stream>>>(
            (const float4*)X, (const float4*)W, bias, S, Sb, cs, stx);
        k_edges_f32<<<2048, 256, 0, stream>>>(rows, cols, adj, S, m2, tr, left);
    }
    k_final<<<1, 256, 0, stream>>>(cs, left, m2, tr, stx, out);
}

// Round 8
// 235.705 us; speedup vs baseline: 1.0798x; 1.0369x over previous
//
#include <hip/hip_runtime.h>

#define N_NODES 100000
#define DIM 256
#define KC 16
#define NE 3200000
#define CHUNK 64
#define NCHUNKS ((N_NODES + CHUNK - 1) / CHUNK)   // 1563 (last chunk = 32 nodes)
#define NSTRIPE 8

// LDS layout strides (u16 units)
#define D0STR 1168   // per 16-dim block: 8 groups * 144 + 16 pad  (2336 B)
#define GSTR  144    // per 8-node group: 8*16 + 16 pad            (288 B)
#define PSTR  72     // P' row stride (64 nodes + 8 pad)           (144 B)

using bf16x8 = __attribute__((ext_vector_type(8))) short;
using f32x4  = __attribute__((ext_vector_type(4))) float;

__device__ __forceinline__ unsigned short f2bf(float f) {  // RNE
    unsigned u = __float_as_uint(f);
    return (unsigned short)((u + 0x7fffu + ((u >> 16) & 1u)) >> 16);
}
__device__ __forceinline__ unsigned packbf(float a, float b) {
    return (unsigned)f2bf(a) | ((unsigned)f2bf(b) << 16);
}

// ---------------------------------------------------------------------------
// Fused assignment + S^T X, both phases MFMA. One chunk per block (grid 1563).
//  stage/phase A/phase B: identical to round 6 (wave-owned rows, no pre-A
//  barrier) — three structural variants all measured 60-62us, exonerating
//  this path.
//  epilogue: STRIPED atomics. r4 counters showed stx atomicAdd = 4B HBM RMW;
//  6.4M adds onto 256 cache lines = ~25K serialized adds/line (~the 60us
//  floor). Block adds into copy (blockIdx&7): 16x less per-line contention.
// ---------------------------------------------------------------------------
template <bool WRITE_PACK>
__global__ __launch_bounds__(256, 4) void k_assign_stx(const float4* __restrict__ X4,
                                                       const float4* __restrict__ W4,
                                                       const float* __restrict__ bias,
                                                       float* __restrict__ S,
                                                       unsigned* __restrict__ Sb,
                                                       float* __restrict__ cs8,
                                                       float* __restrict__ stx8) {
    __shared__ __align__(16) unsigned short Xs[16 * D0STR];   // 37376 B
    __shared__ __align__(16) unsigned short psb[16 * PSTR];   // 2304 B
    __shared__ float csred[4][KC];                            // 256 B -> 39936 B total

    const int lane = threadIdx.x & 63;
    const int wv   = threadIdx.x >> 6;
    const int c    = lane & 15;
    const int quad = lane >> 4;

    const int base = blockIdx.x * CHUNK;
    const int cpy  = blockIdx.x & (NSTRIPE - 1);

    // ---- W -> 8 register frags first (4KB, L2-hot after first blocks)
    bf16x8 wfrag[8];
    #pragma unroll
    for (int s = 0; s < 8; s++) {
        float4 wa = W4[c * 64 + s * 8 + quad * 2];
        float4 wb = W4[c * 64 + s * 8 + quad * 2 + 1];
        union { bf16x8 v; unsigned u[4]; } wf;
        wf.u[0] = packbf(wa.x, wa.y);
        wf.u[1] = packbf(wa.z, wa.w);
        wf.u[2] = packbf(wb.x, wb.y);
        wf.u[3] = packbf(wb.z, wb.w);
        wfrag[s] = wf.v;
    }
    const float4 b4 = ((const float4*)bias)[quad];

    // ---- stage: wave wv owns rows wv*16..wv*16+15; 16 loads in flight
    const int c4 = lane;                // 0..63: f4 column within row
    const int d0s = c4 >> 2;
    const int wo  = (c4 & 3) * 4;
    float4 xr[16];
    #pragma unroll
    for (int s = 0; s < 16; s++) {
        int rg = base + wv * 16 + s;
        if (rg >= N_NODES) rg = N_NODES - 1;
        xr[s] = X4[(size_t)rg * 64 + c4];
    }
    #pragma unroll
    for (int s = 0; s < 16; s++) {
        int r = wv * 16 + s;
        *(uint2*)&Xs[d0s * D0STR + (r >> 3) * GSTR + (r & 7) * 16 + wo] =
            make_uint2(packbf(xr[s].x, xr[s].y), packbf(xr[s].z, xr[s].w));
    }
    // NO __syncthreads: phase A consumes only this wave's own rows.

    // ---- phase A: logits^T (D[m=cluster][n=node]); B-frag = node's dims
    f32x4 la = {0.f, 0.f, 0.f, 0.f};
    {
        const int node = wv * 16 + c;
        const int gA = node >> 3, n8 = node & 7;
        #pragma unroll
        for (int s = 0; s < 8; s++) {
            const int d0 = 2 * s + (quad >> 1);
            bf16x8 xf = *(const bf16x8*)&Xs[d0 * D0STR + gA * GSTR + n8 * 16 + (quad & 1) * 8];
            la = __builtin_amdgcn_mfma_f32_16x16x32_bf16(wfrag[s], xf, la, 0, 0, 0);
        }
    }
    // softmax over clusters (4 regs x 4 quads)
    float lg0 = la[0] + b4.x, lg1 = la[1] + b4.y;
    float lg2 = la[2] + b4.z, lg3 = la[3] + b4.w;
    float mx = fmaxf(fmaxf(lg0, lg1), fmaxf(lg2, lg3));
    mx = fmaxf(mx, __shfl_xor(mx, 16));
    mx = fmaxf(mx, __shfl_xor(mx, 32));
    float e0 = __expf(lg0 - mx), e1 = __expf(lg1 - mx);
    float e2 = __expf(lg2 - mx), e3 = __expf(lg3 - mx);
    float ssum = e0 + e1 + e2 + e3;
    ssum += __shfl_xor(ssum, 16);
    ssum += __shfl_xor(ssum, 32);
    float inv = 1.f / ssum;
    float pvv[4] = {e0 * inv, e1 * inv, e2 * inv, e3 * inv};

    const int nn = wv * 16 + c;
    const int nd = base + nn;
    if (nd >= N_NODES) {
        pvv[0] = pvv[1] = pvv[2] = pvv[3] = 0.f;
    } else {
        *(float4*)&S[(size_t)nd * KC + quad * 4] =
            make_float4(pvv[0], pvv[1], pvv[2], pvv[3]);
        if (WRITE_PACK) {
            unsigned q0 = __float2uint_rn(pvv[0] * 255.f);
            unsigned q1 = __float2uint_rn(pvv[1] * 255.f);
            unsigned q2 = __float2uint_rn(pvv[2] * 255.f);
            unsigned q3 = __float2uint_rn(pvv[3] * 255.f);
            Sb[(size_t)nd * 4 + quad] = q0 | (q1 << 8) | (q2 << 16) | (q3 << 24);
        }
    }
    float csr[4];
    #pragma unroll
    for (int r = 0; r < 4; r++) {
        psb[(quad * 4 + r) * PSTR + nn] = f2bf(pvv[r]);
        csr[r] = pvv[r];
    }
    __syncthreads();   // psb ready + Xs visible cross-wave for phase B

    // ---- phase B: acc += P' · X  (M=cluster, N=dim-tile, K=64 nodes)
    f32x4 acc[4];
    #pragma unroll
    for (int t = 0; t < 4; t++) acc[t] = (f32x4){0.f, 0.f, 0.f, 0.f};
    bf16x8 afH[2];
    afH[0] = *(const bf16x8*)&psb[c * PSTR + 0 * 32 + quad * 8];
    afH[1] = *(const bf16x8*)&psb[c * PSTR + 1 * 32 + quad * 8];
    #pragma unroll
    for (int t = 0; t < 4; t++) {
        const int d0  = wv * 4 + t;
        const int dlo = c;                       // dim = d0*16 + c
        union { bf16x8 v; unsigned short h[8]; } bf0, bf1;
        #pragma unroll
        for (int j = 0; j < 8; j++) {
            const int n0 = quad * 8 + j;         // ks=0: nodes 0..31
            bf0.h[j] = Xs[d0 * D0STR + (n0 >> 3) * GSTR + (n0 & 7) * 16 + dlo];
            const int n1 = 32 + n0;              // ks=1: nodes 32..63
            bf1.h[j] = Xs[d0 * D0STR + (n1 >> 3) * GSTR + (n1 & 7) * 16 + dlo];
        }
        acc[t] = __builtin_amdgcn_mfma_f32_16x16x32_bf16(afH[0], bf0.v, acc[t], 0, 0, 0);
        acc[t] = __builtin_amdgcn_mfma_f32_16x16x32_bf16(afH[1], bf1.v, acc[t], 0, 0, 0);
    }

    // ---- epilogue: striped atomics (copy = blockIdx & 7)
    float* stx_c = stx8 + cpy * (KC * DIM);
    #pragma unroll
    for (int t = 0; t < 4; t++) {
        #pragma unroll
        for (int r = 0; r < 4; r++)
            atomicAdd(&stx_c[(quad * 4 + r) * DIM + (wv * 4 + t) * 16 + c], acc[t][r]);
    }

    float csr2[4];
    #pragma unroll
    for (int r = 0; r < 4; r++) {
        float v = csr[r];
        v += __shfl_xor(v, 1); v += __shfl_xor(v, 2);
        v += __shfl_xor(v, 4); v += __shfl_xor(v, 8);
        csr2[r] = v;
    }
    if (c == 0) {
        #pragma unroll
        for (int r = 0; r < 4; r++) csred[wv][quad * 4 + r] = csr2[r];
    }
    __syncthreads();
    if (threadIdx.x < KC) {
        int t = threadIdx.x;
        atomicAdd(&cs8[cpy * KC + t],
                  csred[0][t] + csred[1][t] + csred[2][t] + csred[3][t]);
    }
}

// ---------------------------------------------------------------------------
// Per-edge fused (u8-packed S): one uint4 gather per node, 2 edges/iter.
// ---------------------------------------------------------------------------
__device__ __forceinline__ void edge_acc_u8(uint4 qr, uint4 qc, float a,
                                            float (&lf)[KC], float& m2l, float& trl) {
    union { uint4 v; unsigned w[4]; } R, C;
    R.v = qr; C.v = qc;
    float dd = 0.f;
    #pragma unroll
    for (int q = 0; q < 4; q++) {
        unsigned x = R.w[q], y = C.w[q];
        float s0 = (float)(x & 0xffu);
        float s1 = (float)((x >> 8) & 0xffu);
        float s2 = (float)((x >> 16) & 0xffu);
        float s3 = (float)(x >> 24);
        float c0 = (float)(y & 0xffu);
        float c1 = (float)((y >> 8) & 0xffu);
        float c2 = (float)((y >> 16) & 0xffu);
        float c3 = (float)(y >> 24);
        dd = fmaf(s0, c0, dd); dd = fmaf(s1, c1, dd);
        dd = fmaf(s2, c2, dd); dd = fmaf(s3, c3, dd);
        lf[4 * q + 0] = fmaf(a, s0, lf[4 * q + 0]);
        lf[4 * q + 1] = fmaf(a, s1, lf[4 * q + 1]);
        lf[4 * q + 2] = fmaf(a, s2, lf[4 * q + 2]);
        lf[4 * q + 3] = fmaf(a, s3, lf[4 * q + 3]);
    }
    m2l += a;
    trl = fmaf(a, dd, trl);
}

__global__ __launch_bounds__(256) void k_edges_u8(const int* __restrict__ rows,
                                                  const int* __restrict__ cols,
                                                  const float* __restrict__ adj,
                                                  const uint4* __restrict__ Sb4,
                                                  float* __restrict__ m2_g,
                                                  float* __restrict__ tr_g,
                                                  float* __restrict__ left_g) {
    float m2l = 0.f, trl = 0.f;
    float lf[KC];
    #pragma unroll
    for (int k = 0; k < KC; k++) lf[k] = 0.f;

    const int NU = NE / 2;
    const int stride = gridDim.x * blockDim.x;
    for (int u = blockIdx.x * blockDim.x + threadIdx.x; u < NU; u += stride) {
        int2   r2 = *(const int2*)(rows + 2 * (size_t)u);
        int2   c2 = *(const int2*)(cols + 2 * (size_t)u);
        float2 a2 = *(const float2*)(adj + 2 * (size_t)u);
        uint4 qr0 = Sb4[r2.x];
        uint4 qc0 = Sb4[c2.x];
        uint4 qr1 = Sb4[r2.y];
        uint4 qc1 = Sb4[c2.y];
        edge_acc_u8(qr0, qc0, a2.x, lf, m2l, trl);
        edge_acc_u8(qr1, qc1, a2.y, lf, m2l, trl);
    }

    trl *= (1.f / 65025.f);
    #pragma unroll
    for (int k = 0; k < KC; k++) lf[k] *= (1.f / 255.f);

    #pragma unroll
    for (int off = 32; off >= 1; off >>= 1) {
        m2l += __shfl_xor(m2l, off);
        trl += __shfl_xor(trl, off);
    }
    #pragma unroll
    for (int k = 0; k < KC; k++) {
        float v = lf[k];
        #pragma unroll
        for (int off = 32; off >= 1; off >>= 1) v += __shfl_xor(v, off);
        lf[k] = v;
    }
    __shared__ float red[4][18];
    int w = threadIdx.x >> 6;
    if ((threadIdx.x & 63) == 0) {
        red[w][0] = m2l; red[w][1] = trl;
        #pragma unroll
        for (int k = 0; k < KC; k++) red[w][2 + k] = lf[k];
    }
    __syncthreads();
    int t = threadIdx.x;
    if (t < 18) {
        float v = red[0][t] + red[1][t] + red[2][t] + red[3][t];
        float* dst = (t == 0) ? m2_g : (t == 1) ? tr_g : &left_g[t - 2];
        atomicAdd(dst, v);
    }
}

// ---------------------------------------------------------------------------
// f32 fallback edge kernel (workspace too small for Sb)
// ---------------------------------------------------------------------------
__global__ __launch_bounds__(256) void k_edges_f32(const int* __restrict__ rows,
                                                   const int* __restrict__ cols,
                                                   const float* __restrict__ adj,
                                                   const float* __restrict__ S,
                                                   float* __restrict__ m2_g,
                                                   float* __restrict__ tr_g,
                                                   float* __restrict__ left_g) {
    float m2l = 0.f, trl = 0.f;
    float lf[KC];
    #pragma unroll
    for (int k = 0; k < KC; k++) lf[k] = 0.f;

    int stride = gridDim.x * blockDim.x;
    for (int e = blockIdx.x * blockDim.x + threadIdx.x; e < NE; e += stride) {
        int r = rows[e], c = cols[e];
        float a = adj[e];
        float sv[KC], cv[KC];
        const float4* sr = (const float4*)(S + (size_t)r * KC);
        const float4* sc = (const float4*)(S + (size_t)c * KC);
        #pragma unroll
        for (int qq = 0; qq < 4; qq++) {
            float4 s4 = sr[qq], c4 = sc[qq];
            sv[4*qq]=s4.x; sv[4*qq+1]=s4.y; sv[4*qq+2]=s4.z; sv[4*qq+3]=s4.w;
            cv[4*qq]=c4.x; cv[4*qq+1]=c4.y; cv[4*qq+2]=c4.z; cv[4*qq+3]=c4.w;
        }
        float dd = 0.f;
        #pragma unroll
        for (int k = 0; k < KC; k++) {
            dd += sv[k] * cv[k];
            lf[k] += a * sv[k];
        }
        m2l += a;
        trl += a * dd;
    }

    #pragma unroll
    for (int off = 32; off >= 1; off >>= 1) {
        m2l += __shfl_xor(m2l, off);
        trl += __shfl_xor(trl, off);
    }
    #pragma unroll
    for (int k = 0; k < KC; k++) {
        float v = lf[k];
        #pragma unroll
        for (int off = 32; off >= 1; off >>= 1) v += __shfl_xor(v, off);
        lf[k] = v;
    }
    __shared__ float red[4][18];
    int w = threadIdx.x >> 6;
    if ((threadIdx.x & 63) == 0) {
        red[w][0] = m2l; red[w][1] = trl;
        #pragma unroll
        for (int k = 0; k < KC; k++) red[w][2 + k] = lf[k];
    }
    __syncthreads();
    int t = threadIdx.x;
    if (t < 18) {
        float v = red[0][t] + red[1][t] + red[2][t] + red[3][t];
        float* dst = (t == 0) ? m2_g : (t == 1) ? tr_g : &left_g[t - 2];
        atomicAdd(dst, v);
    }
}

// ---------------------------------------------------------------------------
// epilogue: sum 8 stripe copies; selu(stx/cs); losses
// ---------------------------------------------------------------------------
__global__ __launch_bounds__(256) void k_final(const float* __restrict__ cs8,
                                               const float* __restrict__ left,
                                               const float* __restrict__ m2p,
                                               const float* __restrict__ trp,
                                               const float* __restrict__ stx8,
                                               float* __restrict__ out) {
    __shared__ float csl[KC];
    int t = threadIdx.x;
    if (t < KC) {
        float v = 0.f;
        #pragma unroll
        for (int cpy = 0; cpy < NSTRIPE; cpy++) v += cs8[cpy * KC + t];
        csl[t] = v;
    }
    __syncthreads();
    #pragma unroll
    for (int k = 0; k < KC; k++) {
        float v = 0.f;
        #pragma unroll
        for (int cpy = 0; cpy < NSTRIPE; cpy++) v += stx8[cpy * (KC * DIM) + k * DIM + t];
        v /= csl[k];
        float r = (v > 0.f) ? 1.0507009873554805f * v
                            : 1.7580993408473766f * (__expf(v) - 1.f);
        out[k * DIM + t] = r;
    }
    if (t == 0) {
        float m2 = *m2p;
        float tn = 0.f;
        #pragma unroll
        for (int k = 0; k < KC; k++) tn += left[k] * left[k];
        tn /= m2;
        float spectral = -((*trp) - tn) / m2;
        float ss = 0.f;
        #pragma unroll
        for (int k = 0; k < KC; k++) ss += csl[k] * csl[k];
        float collapse = 0.1f * (sqrtf(ss) / (float)N_NODES * 4.0f - 1.0f);
        out[KC * DIM + (size_t)N_NODES * KC]     = spectral;
        out[KC * DIM + (size_t)N_NODES * KC + 1] = collapse;
    }
}

extern "C" void kernel_launch(void* const* d_in, const int* in_sizes, int n_in,
                              void* d_out, int out_size, void* d_ws, size_t ws_size,
                              hipStream_t stream) {
    (void)out_size;

    const float* X    = nullptr;
    const int*   ei   = nullptr;
    const float* adj  = nullptr;
    const float* W    = nullptr;
    const float* bias = nullptr;
    for (int i = 0; i < n_in; i++) {
        switch (in_sizes[i]) {
            case 25600000: X    = (const float*)d_in[i]; break;
            case  6400000: ei   = (const int*)d_in[i];   break;
            case  3200000: adj  = (const float*)d_in[i]; break;
            case     4096: W    = (const float*)d_in[i]; break;
            case       16: bias = (const float*)d_in[i]; break;
        }
    }

    float* out = (float*)d_out;
    float* S   = out + KC * DIM;    // assignments [100000,16] f32
    const int* rows = ei;
    const int* cols = ei + NE;

    // ws layout: cs8[8][16] | left[16] | m2 | tr | pad | stx8[8][4096] | Sb
    float* ws   = (float*)d_ws;
    float* cs8  = ws;                       // 128 floats
    float* left = ws + 128;                 // 16
    float* m2   = ws + 144;
    float* tr   = ws + 145;
    float* stx8 = ws + 192;                 // 8 * 4096 floats
    unsigned* Sb = (unsigned*)(ws + 192 + NSTRIPE * KC * DIM);
    const size_t zero_floats = 192 + NSTRIPE * KC * DIM;
    const size_t need = zero_floats * sizeof(float) + (size_t)N_NODES * 16;
    const bool use_pack = (ws_size >= need);   // fixed per process -> graph-safe

    hipMemsetAsync(d_ws, 0, zero_floats * sizeof(float), stream);

    if (use_pack) {
        k_assign_stx<true><<<NCHUNKS, 256, 0, stream>>>(
            (const float4*)X, (const float4*)W, bias, S, Sb, cs8, stx8);
        k_edges_u8<<<2048, 256, 0, stream>>>(rows, cols, adj, (const uint4*)Sb,
                                             m2, tr, left);
    } else {
        k_assign_stx<false><<<NCHUNKS, 256, 0, stream>>>(
            (const float4*)X, (const float4*)W, bias, S, Sb, cs8, stx8);
        k_edges_f32<<<2048, 256, 0, stream>>>(rows, cols, adj, S, m2, tr, left);
    }
    k_final<<<1, 256, 0, stream>>>(cs8, left, m2, tr, stx8, out);
}